// Round 5
// baseline (243.441 us; speedup 1.0000x reference)
//
#include <hip/hip_runtime.h>
#include <hip/hip_bf16.h>
#include <stdint.h>

// WindowAttention: B_=4096 windows, N=64 tokens, C=192, H=6 heads, hd=32.
// One block per window, 4 waves. bf16 MFMA 16x16x32, fp32 accum.
// Round 5: head-PAIR cycles (dual independent softmax chains per segment),
// kh/vth union LDS buffer (33.8 KB, 4 blocks/CU), hardware cvt_pk bf16 packing.

#define NTOK 64
#define CDIM 192
#define KVROW 72          // khv row stride (shorts): 144 B (16B-aligned, rotates banks)

typedef __attribute__((ext_vector_type(4))) float f32x4;
typedef __attribute__((ext_vector_type(8))) short bf16x8;

__device__ __forceinline__ short f2bf(float f) {
  __hip_bfloat16 h = __float2bfloat16(f);          // RNE, hw cvt
  return *reinterpret_cast<short*>(&h);
}
__device__ __forceinline__ uint32_t pack2(float a, float b) {
  __hip_bfloat162 h2;
  h2.x = __float2bfloat16(a);
  h2.y = __float2bfloat16(b);                      // pairs fuse to v_cvt_pk_bf16_f32
  return *reinterpret_cast<uint32_t*>(&h2);
}

// Cross-lane transpose (validated r2-r4): build bf16x8 fragment via shfl.
__device__ __forceinline__ bf16x8 xpose(uint32_t A0, uint32_t A1,
                                        uint32_t B0, uint32_t B1,
                                        int s0, int s1, int hiSel) {
  uint32_t w[4];
  uint32_t a, b;
  a = (uint32_t)__shfl((int)A0, s0); b = (uint32_t)__shfl((int)B0, s0); w[0] = hiSel ? b : a;
  a = (uint32_t)__shfl((int)A1, s0); b = (uint32_t)__shfl((int)B1, s0); w[1] = hiSel ? b : a;
  a = (uint32_t)__shfl((int)A0, s1); b = (uint32_t)__shfl((int)B0, s1); w[2] = hiSel ? b : a;
  a = (uint32_t)__shfl((int)A1, s1); b = (uint32_t)__shfl((int)B1, s1); w[3] = hiSel ? b : a;
  return *reinterpret_cast<bf16x8*>(w);
}

#define GLOAD16(g, l) __builtin_amdgcn_global_load_lds( \
    (const __attribute__((address_space(1))) void*)(g), \
    (__attribute__((address_space(3))) void*)(l), 16, 0, 0)

// Pre-convert + pre-swizzle weights into 12 chunks of 64x192 bf16.
// chunks: 0..2 Wq | 3+2p Wk-pair p | 4+2p Wv-pair p | 9..11 Wp
// Slot swizzle within chunk: s' = (s&24) | ((s^row)&7), 16B slots.
__global__ void wconv_kernel(const float* __restrict__ qkv_w,
                             const float* __restrict__ proj_w,
                             short* __restrict__ ws) {
  const int r = blockIdx.x, c = threadIdx.x;   // 768 x 192
  int chunk, lr;
  float val;
  if (r < 192)      { chunk = r >> 6;                     lr = r & 63;          val = qkv_w[r * CDIM + c]; }
  else if (r < 384) { int q = r - 192; chunk = 3 + 2 * (q >> 6); lr = q & 63;   val = qkv_w[r * CDIM + c]; }
  else if (r < 576) { int q = r - 384; chunk = 4 + 2 * (q >> 6); lr = q & 63;   val = qkv_w[r * CDIM + c]; }
  else              { int q = r - 576; chunk = 9 + (q >> 6);     lr = q & 63;   val = proj_w[q * CDIM + c]; }
  const int s = c >> 3, lo = c & 7;
  const int sp = (s & 24) | ((s ^ lr) & 7);
  ws[chunk * 12288 + lr * CDIM + sp * 8 + lo] = f2bf(val);
}

// Issue 24KB chunk: global (pre-swizzled) -> LDS linear, no VGPR round-trip.
__device__ __forceinline__ void stage_issue(short* __restrict__ wbuf,
                                            const short* __restrict__ src, int tid) {
  const int w = tid >> 6, lane = tid & 63;
  #pragma unroll
  for (int it = 0; it < 6; ++it) {
    const int cidx = it * 4 + w;               // wave-uniform 1KB chunk id
    GLOAD16(src + cidx * 512 + lane * 8, wbuf + cidx * 512);
  }
}

__global__ __launch_bounds__(256, 4)
void winattn_kernel(const float* __restrict__ x, const float* __restrict__ mask,
                    const short* __restrict__ ws,
                    const float* __restrict__ qkv_b, const float* __restrict__ proj_b,
                    float* __restrict__ out) {
  __shared__ __align__(16) short wbuf[64 * CDIM];   // linear [64][192], swizzled content
  __shared__ __align__(16) short khv[NTOK * KVROW]; // union: K [tok][64ch] / V^T [64ch][tok]

  const int b    = blockIdx.x;
  const int tid  = threadIdx.x;
  const int lane = tid & 63;
  const int l16  = lane & 15;
  const int g4   = lane >> 4;
  const int m0   = (tid >> 6) * 16;
  const float scale = 0.17677669529663687f;  // 32^-0.5
  const int s0 = (((2 * g4) & 3) << 4) + l16;
  const int s1 = (((2 * g4 + 1) & 3) << 4) + l16;
  const int hiSel = g4 >> 1;

  // per-lane swizzled slot offsets (shorts): row&7 == l16&7 for all chunk reads
  int soff[6];
  #pragma unroll
  for (int ks = 0; ks < 6; ++ks) {
    const int s = ks * 4 + g4;
    soff[ks] = ((s & 24) | ((s ^ l16) & 7)) << 3;
  }

  // ---- prologue: kick off Wq-chunk-0 staging, then x->af ----
  stage_issue(wbuf, ws, tid);

  const float* xr = x + (size_t)b * (NTOK * CDIM) + (m0 + l16) * CDIM;
  bf16x8 af[6];
  #pragma unroll
  for (int ks = 0; ks < 6; ++ks) {
    const float4 v0 = *reinterpret_cast<const float4*>(xr + ks * 32 + g4 * 8);
    const float4 v1 = *reinterpret_cast<const float4*>(xr + ks * 32 + g4 * 8 + 4);
    uint32_t t[4];
    t[0] = pack2(v0.x, v0.y); t[1] = pack2(v0.z, v0.w);
    t[2] = pack2(v1.x, v1.y); t[3] = pack2(v1.z, v1.w);
    af[ks] = *reinterpret_cast<bf16x8*>(t);
  }
  const float* mrowl = mask + (size_t)b * (NTOK * NTOK) + (m0 + l16) * NTOK;

  __syncthreads();                             // Wq0 resident

  // ---- q phase: q^T = mfma(Wq, x) -> aq[] in registers (scale folded) ----
  bf16x8 aq[6];
  #pragma unroll
  for (int c = 0; c < 3; ++c) {
    uint32_t u[4][2];
    #pragma unroll
    for (int lct = 0; lct < 4; ++lct) {
      f32x4 acc = {0.f, 0.f, 0.f, 0.f};
      #pragma unroll
      for (int ks = 0; ks < 6; ++ks) {
        bf16x8 wf = *reinterpret_cast<const bf16x8*>(wbuf + (lct * 16 + l16) * CDIM + soff[ks]);
        acc = __builtin_amdgcn_mfma_f32_16x16x32_bf16(wf, af[ks], acc, 0, 0, 0);
      }
      const float4 bq = *reinterpret_cast<const float4*>(qkv_b + 64 * c + 16 * lct + 4 * g4);
      u[lct][0] = pack2((acc[0] + bq.x) * scale, (acc[1] + bq.y) * scale);
      u[lct][1] = pack2((acc[2] + bq.z) * scale, (acc[3] + bq.w) * scale);
    }
    __syncthreads();                           // wbuf readers done (all waves)
    stage_issue(wbuf, ws + (c < 2 ? (c + 1) : 3) * 12288, tid);  // next Wq or Wk-pair0
    aq[2 * c]     = xpose(u[0][0], u[0][1], u[1][0], u[1][1], s0, s1, hiSel);
    aq[2 * c + 1] = xpose(u[2][0], u[2][1], u[3][0], u[3][1], s0, s1, hiSel);
    __syncthreads();                           // next chunk resident
  }

  // ---- head-pair loop: p covers heads 2p, 2p+1 ----
  bf16x8 of[6];
  #pragma unroll
  for (int p = 0; p < 3; ++p) {
    // == cycle A: K-GEMM pair (wbuf = Wk rows for heads 2p,2p+1) ==
    #pragma unroll
    for (int lct = 0; lct < 4; ++lct) {
      f32x4 acc = {0.f, 0.f, 0.f, 0.f};
      #pragma unroll
      for (int ks = 0; ks < 6; ++ks) {
        bf16x8 wf = *reinterpret_cast<const bf16x8*>(wbuf + (lct * 16 + l16) * CDIM + soff[ks]);
        acc = __builtin_amdgcn_mfma_f32_16x16x32_bf16(wf, af[ks], acc, 0, 0, 0);
      }
      const float4 bk4 = *reinterpret_cast<const float4*>(qkv_b + 192 + 64 * p + 16 * lct + 4 * g4);
      uint2 kw;
      kw.x = pack2(acc[0] + bk4.x, acc[1] + bk4.y);
      kw.y = pack2(acc[2] + bk4.z, acc[3] + bk4.w);
      *reinterpret_cast<uint2*>(khv + (m0 + l16) * KVROW + 16 * lct + 4 * g4) = kw;
    }
    __syncthreads();                           // K ready; wbuf readers done
    stage_issue(wbuf, ws + (4 + 2 * p) * 12288, tid);   // Wv pair

    float4 mreg[4];
    #pragma unroll
    for (int rt = 0; rt < 4; ++rt)
      mreg[rt] = *reinterpret_cast<const float4*>(mrowl + 16 * rt + 4 * g4);

    // dual QK + softmax (two independent chains)
    bf16x8 bp[2][2];
    #pragma unroll
    for (int e = 0; e < 2; ++e) {
      float pr[4][4];
      float rmax = -1e30f;
      #pragma unroll
      for (int rt = 0; rt < 4; ++rt) {
        bf16x8 bk = *reinterpret_cast<const bf16x8*>(khv + (rt * 16 + l16) * KVROW + 32 * e + g4 * 8);
        f32x4 z = {0.f, 0.f, 0.f, 0.f};
        f32x4 s = __builtin_amdgcn_mfma_f32_16x16x32_bf16(bk, aq[2 * p + e], z, 0, 0, 0);
        pr[rt][0] = s[0] + mreg[rt].x; pr[rt][1] = s[1] + mreg[rt].y;
        pr[rt][2] = s[2] + mreg[rt].z; pr[rt][3] = s[3] + mreg[rt].w;
        #pragma unroll
        for (int i = 0; i < 4; ++i) rmax = fmaxf(rmax, pr[rt][i]);
      }
      rmax = fmaxf(rmax, __shfl_xor(rmax, 16));
      rmax = fmaxf(rmax, __shfl_xor(rmax, 32));
      float rsum = 0.f;
      #pragma unroll
      for (int rt = 0; rt < 4; ++rt)
        #pragma unroll
        for (int i = 0; i < 4; ++i) { pr[rt][i] = __expf(pr[rt][i] - rmax); rsum += pr[rt][i]; }
      rsum += __shfl_xor(rsum, 16);
      rsum += __shfl_xor(rsum, 32);
      const float rinv = 1.f / rsum;
      uint32_t wpk[4][2];
      #pragma unroll
      for (int rt = 0; rt < 4; ++rt) {
        wpk[rt][0] = pack2(pr[rt][0] * rinv, pr[rt][1] * rinv);
        wpk[rt][1] = pack2(pr[rt][2] * rinv, pr[rt][3] * rinv);
      }
      bp[e][0] = xpose(wpk[0][0], wpk[0][1], wpk[1][0], wpk[1][1], s0, s1, hiSel);
      bp[e][1] = xpose(wpk[2][0], wpk[2][1], wpk[3][0], wpk[3][1], s0, s1, hiSel);
    }
    __syncthreads();                           // Wv resident; K readers done

    // == cycle B: V-GEMM pair -> khv as V^T [ch][tok] ==
    #pragma unroll
    for (int lct = 0; lct < 4; ++lct) {
      f32x4 acc = {0.f, 0.f, 0.f, 0.f};
      #pragma unroll
      for (int ks = 0; ks < 6; ++ks) {
        bf16x8 wf = *reinterpret_cast<const bf16x8*>(wbuf + (lct * 16 + l16) * CDIM + soff[ks]);
        acc = __builtin_amdgcn_mfma_f32_16x16x32_bf16(af[ks], wf, acc, 0, 0, 0);
      }
      const float bv = qkv_b[384 + 64 * p + 16 * lct + l16];
      uint2 vw;
      vw.x = pack2(acc[0] + bv, acc[1] + bv);
      vw.y = pack2(acc[2] + bv, acc[3] + bv);
      *reinterpret_cast<uint2*>(khv + (16 * lct + l16) * KVROW + m0 + 4 * g4) = vw;
    }
    __syncthreads();                           // V^T ready; wbuf readers done
    stage_issue(wbuf, ws + (p < 2 ? (5 + 2 * p) : 9) * 12288, tid);  // next Wk-pair or Wp0

    // dual PV
    #pragma unroll
    for (int e = 0; e < 2; ++e) {
      uint32_t uo[2][2];
      #pragma unroll
      for (int ct2 = 0; ct2 < 2; ++ct2) {
        const short* vb = khv + (32 * e + 16 * ct2 + l16) * KVROW;
        bf16x8 bv1 = *reinterpret_cast<const bf16x8*>(vb + g4 * 8);
        bf16x8 bv2 = *reinterpret_cast<const bf16x8*>(vb + 32 + g4 * 8);
        f32x4 acc = {0.f, 0.f, 0.f, 0.f};
        acc = __builtin_amdgcn_mfma_f32_16x16x32_bf16(bv1, bp[e][0], acc, 0, 0, 0);
        acc = __builtin_amdgcn_mfma_f32_16x16x32_bf16(bv2, bp[e][1], acc, 0, 0, 0);
        uo[ct2][0] = pack2(acc[0], acc[1]);
        uo[ct2][1] = pack2(acc[2], acc[3]);
      }
      of[2 * p + e] = xpose(uo[0][0], uo[0][1], uo[1][0], uo[1][1], s0, s1, hiSel);
    }
    __syncthreads();                           // next wbuf resident; V readers done
  }

  // ---- proj: 3 chunks, of[] as A-operand; stores hide next-chunk latency ----
  float* og = out + (size_t)b * (NTOK * CDIM);
  #pragma unroll
  for (int c = 0; c < 3; ++c) {
    f32x4 acc[4];
    #pragma unroll
    for (int lct = 0; lct < 4; ++lct) {
      f32x4 a = {0.f, 0.f, 0.f, 0.f};
      #pragma unroll
      for (int ks = 0; ks < 6; ++ks) {
        bf16x8 wf = *reinterpret_cast<const bf16x8*>(wbuf + (lct * 16 + l16) * CDIM + soff[ks]);
        a = __builtin_amdgcn_mfma_f32_16x16x32_bf16(of[ks], wf, a, 0, 0, 0);
      }
      acc[lct] = a;
    }
    if (c < 2) {
      __syncthreads();                         // wbuf readers done
      stage_issue(wbuf, ws + (10 + c) * 12288, tid);
    }
    #pragma unroll
    for (int lct = 0; lct < 4; ++lct) {
      const int cc = 64 * c + 16 * lct + l16;
      const float pb = proj_b[cc];
      #pragma unroll
      for (int i = 0; i < 4; ++i)
        og[(m0 + 4 * g4 + i) * CDIM + cc] = acc[lct][i] + pb;
    }
    if (c < 2) __syncthreads();                // next chunk resident
  }
}

extern "C" void kernel_launch(void* const* d_in, const int* in_sizes, int n_in,
                              void* d_out, int out_size, void* d_ws, size_t ws_size,
                              hipStream_t stream) {
  const float* x      = (const float*)d_in[0];
  const float* mask   = (const float*)d_in[1];
  const float* qkv_w  = (const float*)d_in[2];
  const float* qkv_b  = (const float*)d_in[3];
  const float* proj_w = (const float*)d_in[4];
  const float* proj_b = (const float*)d_in[5];
  float* out = (float*)d_out;

  short* ws = (short*)d_ws;                    // 12 chunks x 12288 shorts = 294912 B

  wconv_kernel<<<768, 192, 0, stream>>>(qkv_w, proj_w, ws);
  winattn_kernel<<<4096, 256, 0, stream>>>(x, mask, ws, qkv_b, proj_b, out);
}